// Round 2
// baseline (136.557 us; speedup 1.0000x reference)
//
#include <hip/hip_runtime.h>
#include <hip/hip_bf16.h>
#include <stdint.h>

// MLP: hidden = X @ W1^T + b1 ; out = hidden @ W2^T + b2
// X [16384,2048] f32, W1 [512,2048], b1 [512], W2 [2048,512], b2 [2048]
// R5: gemm1 was serialized by the per-step __syncthreads vmcnt(0) drain
// (every wave paid full X HBM latency 32x; MfmaUtil 13% with HBM 12% and
// VALU 8% - everything idle). New gemm1: drain-free counted-wait pipeline:
//  - X AND W reg-staged (no global_load_lds) so all vmcnt waits are
//    compiler-counted at the register consumers, never at the barrier
//  - raw s_barrier + lgkmcnt(0) only (global loads live across barriers)
//  - X prefetch depth 2 (xvA/xvB static-named), W depth 1 (L2-warm)
//  - T5 setprio around MFMA cluster (schedule now has role diversity)
// Keep: BK=64 XOR swizzle (0 conflicts), fused X f32->bf16 cast, 512 thr,
// 2x4 waves of 64x32, 64 KB LDS (2 blocks/CU), chunked XCD swizzle.
// GEMM2 unchanged (~900 TF, near m97-structure ceiling).

typedef short bf16x8 __attribute__((ext_vector_type(8)));
typedef float f32x4 __attribute__((ext_vector_type(4)));

static __device__ __forceinline__ unsigned short f32_to_bf16_rne(float f) {
    unsigned int u = __float_as_uint(f);
    u += 0x7fffu + ((u >> 16) & 1u);
    return (unsigned short)(u >> 16);
}

static __device__ __forceinline__ unsigned int cvt_pk_bf16(float lo, float hi) {
    unsigned int r;
    asm("v_cvt_pk_bf16_f32 %0, %1, %2" : "=v"(r) : "v"(lo), "v"(hi));
    return r;  // low 16 = bf16(lo), high 16 = bf16(hi)
}

// lgkmcnt(0)-only barrier: ds ops ordered, global loads stay in flight.
static __device__ __forceinline__ void block_sync_lds() {
    asm volatile("s_waitcnt lgkmcnt(0)" ::: "memory");
    __builtin_amdgcn_sched_barrier(0);
    __builtin_amdgcn_s_barrier();
    __builtin_amdgcn_sched_barrier(0);
}

// one kernel casts both weight matrices (same element count each)
__global__ void cast_weights_bf16(const float* __restrict__ w1,
                                  unsigned short* __restrict__ o1,
                                  const float* __restrict__ w2,
                                  unsigned short* __restrict__ o2, int n4each) {
    int stride = gridDim.x * blockDim.x;
    for (int i = blockIdx.x * blockDim.x + threadIdx.x; i < 2 * n4each;
         i += stride) {
        const float* in = (i < n4each) ? w1 : w2;
        unsigned short* out = (i < n4each) ? o1 : o2;
        int j = (i < n4each) ? i : i - n4each;
        float4 v = ((const float4*)in)[j];
        ushort4 o;
        o.x = f32_to_bf16_rne(v.x);
        o.y = f32_to_bf16_rne(v.y);
        o.z = f32_to_bf16_rne(v.z);
        o.w = f32_to_bf16_rne(v.w);
        ((ushort4*)out)[j] = o;
    }
}

#define GLOAD_LDS16(gsrc, ldst)                                              \
    __builtin_amdgcn_global_load_lds(                                        \
        (const __attribute__((address_space(1))) void*)(gsrc),               \
        (__attribute__((address_space(3))) void*)(ldst), 16, 0, 0)

// ---------------------------------------------------------------------------
// GEMM1: H[16384][512] bf16 = X[16384][2048] f32 @ W1bf[512][2048]^T + b1
// 128x128 tile, 512 thr (2x4 waves of 64x32), BK=64, double-buffered 64 KB.
// grid = 512 blocks = 2 blocks/CU. One raw barrier per K-step, zero vmcnt
// drains in the main loop. Staging geometry (both X and W): thread t ->
// row = t>>2 (0..127), 16B-units u0=(t&3)*2 and u0+1; LDS rows are 128 B,
// phys_unit = logical ^ (row&7)  ->  byte b0, b1 = b0^16.
// ---------------------------------------------------------------------------
__global__ __launch_bounds__(512, 4)
void gemm1_xcast(const float* __restrict__ X,
                 const unsigned short* __restrict__ W1,
                 const float* __restrict__ b1,
                 unsigned short* __restrict__ H) {
    constexpr int K = 2048, N = 512, BK = 64, NSTEP = K / BK;  // 32 steps

    __shared__ __align__(16) unsigned short ldsX[2][128 * BK];  // 2 x 16 KB
    __shared__ __align__(16) unsigned short ldsW[2][128 * BK];  // 2 x 16 KB

    const int tid  = threadIdx.x;
    const int lane = tid & 63;
    const int wid  = tid >> 6;   // 0..7
    const int wr   = wid >> 2;   // 0..1 : 64-row half
    const int wc   = wid & 3;    // 0..3 : 32-col quarter

    // chunked XCD swizzle: nwg = 512 = 8 * 64 -> XCD x gets logical [64x,64x+64)
    const int bid = blockIdx.x;
    const int swz = ((bid & 7) << 6) + (bid >> 3);
    const int bm  = swz >> 2;            // 4 col-blocks of a row-panel adjacent
    const int bn  = swz & 3;
    const int brow = bm << 7;
    const int bcol = bn << 7;

    const int lrow = lane & 15;
    const int ku   = lane >> 4;
    const int rx   = lrow & 7;

    // shared staging geometry for X and W
    const int srow = tid >> 2;                 // 0..127
    const int su0  = (tid & 3) << 1;           // logical unit 0,2,4,6
    const float* xbase = X + (size_t)(brow + srow) * K + (su0 << 3);
    const char*  wbase = (const char*)(W1 + (size_t)(bcol + srow) * K) + (su0 << 4);
    const int b0 = srow * 128 + ((su0 ^ (srow & 7)) << 4);  // byte off in LDS
    const int b1o = b0 ^ 16;                                 // unit su0+1

    f32x4 acc[4][2] = {};
    f32x4 xvA[4], xvB[4];   // in-flight X tiles (16 consecutive floats each)
    uint4 wv0, wv1;         // in-flight W slice (32 B)

    auto loadX = [&](int k0, f32x4* xv) {
        const float* p = xbase + k0;
        xv[0] = *(const f32x4*)p;
        xv[1] = *(const f32x4*)(p + 4);
        xv[2] = *(const f32x4*)(p + 8);
        xv[3] = *(const f32x4*)(p + 12);
    };
    auto loadW = [&](int k0) {
        const char* p = wbase + (size_t)k0 * 2;
        wv0 = *(const uint4*)p;
        wv1 = *(const uint4*)(p + 16);
    };
    auto writeX = [&](const f32x4* xv, unsigned short* bufX) {
        uint4 a, b;
        a.x = cvt_pk_bf16(xv[0][0], xv[0][1]);
        a.y = cvt_pk_bf16(xv[0][2], xv[0][3]);
        a.z = cvt_pk_bf16(xv[1][0], xv[1][1]);
        a.w = cvt_pk_bf16(xv[1][2], xv[1][3]);
        b.x = cvt_pk_bf16(xv[2][0], xv[2][1]);
        b.y = cvt_pk_bf16(xv[2][2], xv[2][3]);
        b.z = cvt_pk_bf16(xv[3][0], xv[3][1]);
        b.w = cvt_pk_bf16(xv[3][2], xv[3][3]);
        *(uint4*)((char*)bufX + b0)  = a;
        *(uint4*)((char*)bufX + b1o) = b;
    };
    auto writeW = [&](unsigned short* bufW) {
        *(uint4*)((char*)bufW + b0)  = wv0;
        *(uint4*)((char*)bufW + b1o) = wv1;
    };
    auto compute = [&](const unsigned short* bufX, const unsigned short* bufW) {
#pragma unroll
        for (int kk = 0; kk < 2; ++kk) {
            const int un = ((ku + (kk << 2)) ^ rx) << 4;
            bf16x8 a[4], b[2];
#pragma unroll
            for (int m = 0; m < 4; ++m)
                a[m] = *(const bf16x8*)((const char*)bufX +
                       ((wr << 6) + (m << 4) + lrow) * 128 + un);
#pragma unroll
            for (int n = 0; n < 2; ++n)
                b[n] = *(const bf16x8*)((const char*)bufW +
                       ((wc << 5) + (n << 4) + lrow) * 128 + un);
            __builtin_amdgcn_s_setprio(1);
#pragma unroll
            for (int m = 0; m < 4; ++m)
#pragma unroll
                for (int n = 0; n < 2; ++n)
                    acc[m][n] = __builtin_amdgcn_mfma_f32_16x16x32_bf16(
                        a[m], b[n], acc[m][n], 0, 0, 0);
            __builtin_amdgcn_s_setprio(0);
        }
    };

    // prologue: tile 0 -> buf0 via regs; prefetch X(1)
    loadW(0);
    loadX(0, xvA);
    writeW(ldsW[0]);       // compiler waits only the 2 W loads
    writeX(xvA, ldsX[0]);  // compiler waits only the 4 X loads
    loadX(BK, xvA);        // X(1) in flight across the barrier
    block_sync_lds();

#pragma unroll 1
    for (int t = 0; t < NSTEP; t += 2) {
        // even step: compute tile t (buf0); stage t+1 -> buf1
        if (t + 2 < NSTEP) loadX((t + 2) * BK, xvB);  // deepest latency first
        loadW((t + 1) * BK);                          // t+1 <= 31 always
        compute(ldsX[0], ldsW[0]);
        writeX(xvA, ldsX[1]);   // xvA = X(t+1), issued a full step ago
        writeW(ldsW[1]);        // wv = W(t+1), issued before compute
        block_sync_lds();

        // odd step: compute tile t+1 (buf1); stage t+2 -> buf0
        const bool m2 = (t + 3 < NSTEP);
        const bool m1 = (t + 2 < NSTEP);
        if (m2) loadX((t + 3) * BK, xvA);
        if (m1) loadW((t + 2) * BK);
        compute(ldsX[1], ldsW[1]);
        if (m1) {
            writeX(xvB, ldsX[0]);
            writeW(ldsW[0]);
        }
        block_sync_lds();
    }

    // epilogue: C/D layout col = lane&15, row = (lane>>4)*4 + j  [m89]
    const int r0 = (lane >> 4) << 2;
#pragma unroll
    for (int n = 0; n < 2; ++n) {
        const int col = bcol + (wc << 5) + (n << 4) + lrow;
        const float bb = b1[col];
#pragma unroll
        for (int m = 0; m < 4; ++m)
#pragma unroll
            for (int j = 0; j < 4; ++j) {
                const int row = brow + (wr << 6) + (m << 4) + r0 + j;
                H[(size_t)row * N + col] = f32_to_bf16_rne(acc[m][n][j] + bb);
            }
    }
}

// ---------------------------------------------------------------------------
// GEMM2: out[16384][2048] f32 = Hbf[16384][512] @ W2bf[2048][512]^T + b2
// 128x128 tile, 256 thr, BK=64, single-buffered 32 KB -> 5 blocks/CU.
// grid = 128*16 = 2048 blocks, chunked XCD swizzle (q=256). (unchanged)
// ---------------------------------------------------------------------------
__global__ __launch_bounds__(256)
void gemm2(const unsigned short* __restrict__ A,
           const unsigned short* __restrict__ Bt,
           const float* __restrict__ bias,
           float* __restrict__ C) {
    constexpr int N = 2048, Kd = 512, BK = 64, NSTEP = Kd / BK;  // 8 steps

    __shared__ __align__(16) unsigned short ldsA[128 * BK];  // 16 KB
    __shared__ __align__(16) unsigned short ldsB[128 * BK];  // 16 KB

    const int tid  = threadIdx.x;
    const int lane = tid & 63;
    const int wid  = tid >> 6;
    const int wr   = wid >> 1;
    const int wc   = wid & 1;

    const int bid = blockIdx.x;
    const int swz = ((bid & 7) << 8) + (bid >> 3);   // nwg=2048, q=256
    const int bn  = swz & 15;
    const int bm  = swz >> 4;
    const int brow = bm << 7;
    const int bcol = bn << 7;

    const int lrow = lane & 15;
    const int ku   = lane >> 4;
    const int rx   = lrow & 7;

    const int srow = tid >> 3;
    const int sgu  = (tid & 7) ^ (srow & 7);

    f32x4 acc[4][4] = {};

    auto stage = [&](int k0) {
#pragma unroll
        for (int i = 0; i < 4; ++i) {
            const int row = i * 32 + srow;
            const char* sa =
                (const char*)(A + (size_t)(brow + row) * Kd + k0) + (sgu << 4);
            const char* sb =
                (const char*)(Bt + (size_t)(bcol + row) * Kd + k0) + (sgu << 4);
            GLOAD_LDS16(sa, (char*)ldsA + i * 4096 + tid * 16);
            GLOAD_LDS16(sb, (char*)ldsB + i * 4096 + tid * 16);
        }
    };
    auto compute = [&]() {
#pragma unroll
        for (int kk = 0; kk < 2; ++kk) {
            const int un = ((ku + (kk << 2)) ^ rx) << 4;
            bf16x8 a[4], b[4];
#pragma unroll
            for (int m = 0; m < 4; ++m)
                a[m] = *(const bf16x8*)((const char*)ldsA +
                       ((wr << 6) + (m << 4) + lrow) * 128 + un);
#pragma unroll
            for (int n = 0; n < 4; ++n)
                b[n] = *(const bf16x8*)((const char*)ldsB +
                       ((wc << 6) + (n << 4) + lrow) * 128 + un);
#pragma unroll
            for (int m = 0; m < 4; ++m)
#pragma unroll
                for (int n = 0; n < 4; ++n)
                    acc[m][n] = __builtin_amdgcn_mfma_f32_16x16x32_bf16(
                        a[m], b[n], acc[m][n], 0, 0, 0);
        }
    };

    stage(0);
    __syncthreads();

    for (int t = 0; t < NSTEP; ++t) {
        compute();
        if (t + 1 < NSTEP) {
            __syncthreads();
            stage((t + 1) * BK);
            __syncthreads();
        }
    }

    const int r0 = (lane >> 4) << 2;
#pragma unroll
    for (int n = 0; n < 4; ++n) {
        const int col = bcol + (wc << 6) + (n << 4) + lrow;
        const float bb = bias[col];
#pragma unroll
        for (int m = 0; m < 4; ++m)
#pragma unroll
            for (int j = 0; j < 4; ++j) {
                const int row = brow + (wr << 6) + (m << 4) + r0 + j;
                C[(size_t)row * N + col] = acc[m][n][j] + bb;
            }
    }
}

extern "C" void kernel_launch(void* const* d_in, const int* in_sizes, int n_in,
                              void* d_out, int out_size, void* d_ws, size_t ws_size,
                              hipStream_t stream) {
    const float* X  = (const float*)d_in[0];   // [16384][2048]
    const float* W1 = (const float*)d_in[1];   // [512][2048]
    const float* b1 = (const float*)d_in[2];   // [512]
    const float* W2 = (const float*)d_in[3];   // [2048][512]
    const float* b2 = (const float*)d_in[4];   // [2048]

    const int B = 16384, M = 2048, Kd = 512;

    // workspace: W1bf (2MB), W2bf (2MB), Hbf (16.8MB)
    char* ws = (char*)d_ws;
    unsigned short* W1bf = (unsigned short*)ws;
    unsigned short* W2bf = W1bf + (size_t)Kd * M;
    unsigned short* Hbf  = W2bf + (size_t)M * Kd;

    // both weight casts in one launch: 2 * 256K float4s, one per thread
    cast_weights_bf16<<<2048, 256, 0, stream>>>(W1, W1bf, W2, W2bf,
                                                Kd * M / 4);

    gemm1_xcast<<<(B / 128) * (Kd / 128), 512, 0, stream>>>(X, W1bf, b1, Hbf);
    gemm2<<<(B / 128) * (M / 128), 256, 0, stream>>>(Hbf, W2bf, b2,
                                                     (float*)d_out);
}

// Round 3
// 126.299 us; speedup vs baseline: 1.0812x; 1.0812x over previous
//
#include <hip/hip_runtime.h>
#include <hip/hip_bf16.h>
#include <stdint.h>

// MLP: hidden = X @ W1^T + b1 ; out = hidden @ W2^T + b2
// X [16384,2048] f32, W1 [512,2048], b1 [512], W2 [2048,512], b2 [2048]
// R6: R4/R5 (occupancy, drain-free pipeline) were NEUTRAL -> latency theory
// dead. Real limiter: intra-instruction address scatter of the X (and R5 W)
// global loads. Old map (row=tid>>2, byte=(tid&3)*64) made each 64-lane
// vmem instruction touch 64 cache lines for 1 KB payload -> ~6k cy/step of
// TA/L1 request processing per CU (the missing time; all pipes idle).
// Fix: line-dense staging.
//  - X: lane l of wave w reads contiguous f32x4 at row 16w+(l>>4)+4j,
//    byte (l&15)*16 -> each instruction = 4 contiguous 256B runs (dense).
//    LDS side: 4x ds_write_b64, 16-lane group = one full 128B row, XOR
//    swizzle kept -> every bank exactly 2x (free).
//  - W: back to dense global_load_lds (permuted-contiguous 128B blocks).
// Keep: 512 thr 2x4 waves of 64x32, 64KB dbuf, one __syncthreads/step
// (its vmcnt(0) is ~free now), XOR read swizzle, setprio, XCD swizzle.
// GEMM2 unchanged.

typedef short bf16x8 __attribute__((ext_vector_type(8)));
typedef float f32x4 __attribute__((ext_vector_type(4)));

static __device__ __forceinline__ unsigned short f32_to_bf16_rne(float f) {
    unsigned int u = __float_as_uint(f);
    u += 0x7fffu + ((u >> 16) & 1u);
    return (unsigned short)(u >> 16);
}

static __device__ __forceinline__ unsigned int cvt_pk_bf16(float lo, float hi) {
    unsigned int r;
    asm("v_cvt_pk_bf16_f32 %0, %1, %2" : "=v"(r) : "v"(lo), "v"(hi));
    return r;  // low 16 = bf16(lo), high 16 = bf16(hi)
}

// one kernel casts both weight matrices (same element count each)
__global__ void cast_weights_bf16(const float* __restrict__ w1,
                                  unsigned short* __restrict__ o1,
                                  const float* __restrict__ w2,
                                  unsigned short* __restrict__ o2, int n4each) {
    int stride = gridDim.x * blockDim.x;
    for (int i = blockIdx.x * blockDim.x + threadIdx.x; i < 2 * n4each;
         i += stride) {
        const float* in = (i < n4each) ? w1 : w2;
        unsigned short* out = (i < n4each) ? o1 : o2;
        int j = (i < n4each) ? i : i - n4each;
        float4 v = ((const float4*)in)[j];
        ushort4 o;
        o.x = f32_to_bf16_rne(v.x);
        o.y = f32_to_bf16_rne(v.y);
        o.z = f32_to_bf16_rne(v.z);
        o.w = f32_to_bf16_rne(v.w);
        ((ushort4*)out)[j] = o;
    }
}

#define GLOAD_LDS16(gsrc, ldst)                                              \
    __builtin_amdgcn_global_load_lds(                                        \
        (const __attribute__((address_space(1))) void*)(gsrc),               \
        (__attribute__((address_space(3))) void*)(ldst), 16, 0, 0)

// ---------------------------------------------------------------------------
// GEMM1: H[16384][512] bf16 = X[16384][2048] f32 @ W1bf[512][2048]^T + b1
// 128x128 tile, 512 thr (2x4 waves of 64x32), BK=64, double-buffered 64 KB.
// grid = 512 blocks = 2 blocks/CU. LDS rows are 128 B = 8 x 16B units,
// phys_unit = logical ^ (row&7).
// X staging: wave w, instr j: lane l -> row 16w + 4j + (l>>4), f32x4 at
// float offset (l&15)*4 (q-th quarter of the 256B f32 row-slice).
// LDS: unit u=q>>1 half h=q&1 -> byte row*128 + ((u^(row&7))<<4) + h*8.
// W staging: global_load_lds, thread t -> row i*64+(t>>3), permuted unit
// (t&7)^(row&7), linear dest t*16 (dense 128B blocks).
// ---------------------------------------------------------------------------
__global__ __launch_bounds__(512, 4)
void gemm1_xcast(const float* __restrict__ X,
                 const unsigned short* __restrict__ W1,
                 const float* __restrict__ b1,
                 unsigned short* __restrict__ H) {
    constexpr int K = 2048, N = 512, BK = 64, NSTEP = K / BK;  // 32 steps

    __shared__ __align__(16) unsigned short ldsX[2][128 * BK];  // 2 x 16 KB
    __shared__ __align__(16) unsigned short ldsW[2][128 * BK];  // 2 x 16 KB

    const int tid  = threadIdx.x;
    const int lane = tid & 63;
    const int wid  = tid >> 6;   // 0..7
    const int wr   = wid >> 2;   // 0..1 : 64-row half
    const int wc   = wid & 3;    // 0..3 : 32-col quarter

    // chunked XCD swizzle: nwg = 512 = 8 * 64 -> XCD x gets logical [64x,64x+64)
    const int bid = blockIdx.x;
    const int swz = ((bid & 7) << 6) + (bid >> 3);
    const int bm  = swz >> 2;            // 4 col-blocks of a row-panel adjacent
    const int bn  = swz & 3;
    const int brow = bm << 7;
    const int bcol = bn << 7;

    const int lrow = lane & 15;
    const int ku   = lane >> 4;
    const int rx   = lrow & 7;

    // ---- X staging geometry (line-dense) ----
    const int g  = lane >> 4;          // 0..3 row-in-quad
    const int q  = lane & 15;          // quarter index within 256B row-slice
    const int xrow0 = (wid << 4) + g;  // base row for j=0 (0..127 over waves)
    const float* xbase = X + (size_t)(brow + xrow0) * K + (q << 2);
    const int xu = q >> 1;             // logical 16B LDS unit
    const int xh = (q & 1) << 3;       // byte half within unit
    const int obase = xrow0 * 128 + xh;
    // rows j*4 apart: (row&7) alternates g (j even) / g^4 (j odd)
    const int oeven = obase + ((xu ^ g) << 4);
    const int oodd  = obase + ((xu ^ g ^ 4) << 4);

    // ---- W staging geometry (dense gload_lds) ----
    const int wrow0 = tid >> 3;        // 0..63
    const int wun   = tid & 7;

    f32x4 acc[4][2] = {};
    f32x4 xv[4];  // in-flight X: 4 rows x f32x4 each

    auto loadX = [&](int k0) {
#pragma unroll
        for (int j = 0; j < 4; ++j)
            xv[j] = *(const f32x4*)(xbase + k0 + (size_t)j * 4 * K);
    };
    auto writeX = [&](unsigned short* bufX) {
#pragma unroll
        for (int j = 0; j < 4; ++j) {
            uint2 d;
            d.x = cvt_pk_bf16(xv[j][0], xv[j][1]);
            d.y = cvt_pk_bf16(xv[j][2], xv[j][3]);
            const int off = ((j & 1) ? oodd : oeven) + j * 512;
            *(uint2*)((char*)bufX + off) = d;
        }
    };
    auto stageW = [&](int k0, unsigned short* bufW) {
#pragma unroll
        for (int i = 0; i < 2; ++i) {
            const int row = i * 64 + wrow0;
            const char* src = (const char*)(W1 + (size_t)(bcol + row) * K + k0)
                              + ((wun ^ (row & 7)) << 4);
            GLOAD_LDS16(src, (char*)bufW + i * 8192 + tid * 16);
        }
    };
    auto compute = [&](const unsigned short* bufX, const unsigned short* bufW) {
#pragma unroll
        for (int kk = 0; kk < 2; ++kk) {
            const int un = ((ku + (kk << 2)) ^ rx) << 4;
            bf16x8 a[4], b[2];
#pragma unroll
            for (int m = 0; m < 4; ++m)
                a[m] = *(const bf16x8*)((const char*)bufX +
                       ((wr << 6) + (m << 4) + lrow) * 128 + un);
#pragma unroll
            for (int n = 0; n < 2; ++n)
                b[n] = *(const bf16x8*)((const char*)bufW +
                       ((wc << 5) + (n << 4) + lrow) * 128 + un);
            __builtin_amdgcn_s_setprio(1);
#pragma unroll
            for (int m = 0; m < 4; ++m)
#pragma unroll
                for (int n = 0; n < 2; ++n)
                    acc[m][n] = __builtin_amdgcn_mfma_f32_16x16x32_bf16(
                        a[m], b[n], acc[m][n], 0, 0, 0);
            __builtin_amdgcn_s_setprio(0);
        }
    };

    // prologue: tile 0 -> buf0
    loadX(0);
    stageW(0, ldsW[0]);
    writeX(ldsX[0]);
    __syncthreads();

#pragma unroll 1
    for (int t = 0; t < NSTEP; t += 2) {
        // compute tile t (buf0); stage t+1 -> buf1 (t+1 <= 31 always)
        loadX((t + 1) * BK);
        stageW((t + 1) * BK, ldsW[1]);
        compute(ldsX[0], ldsW[0]);
        writeX(ldsX[1]);   // waits X regs only (W gloads younger, stay in flight)
        __syncthreads();   // vmcnt(0) ~free: W issued a full compute-phase ago

        // compute tile t+1 (buf1); stage t+2 -> buf0
        const bool more = (t + 2 < NSTEP);
        if (more) {
            loadX((t + 2) * BK);
            stageW((t + 2) * BK, ldsW[0]);
        }
        compute(ldsX[1], ldsW[1]);
        if (more) writeX(ldsX[0]);
        __syncthreads();
    }

    // epilogue: C/D layout col = lane&15, row = (lane>>4)*4 + j  [m89]
    const int r0 = (lane >> 4) << 2;
#pragma unroll
    for (int n = 0; n < 2; ++n) {
        const int col = bcol + (wc << 5) + (n << 4) + lrow;
        const float bb = b1[col];
#pragma unroll
        for (int m = 0; m < 4; ++m)
#pragma unroll
            for (int j = 0; j < 4; ++j) {
                const int row = brow + (wr << 6) + (m << 4) + r0 + j;
                H[(size_t)row * N + col] = f32_to_bf16_rne(acc[m][n][j] + bb);
            }
    }
}

// ---------------------------------------------------------------------------
// GEMM2: out[16384][2048] f32 = Hbf[16384][512] @ W2bf[2048][512]^T + b2
// 128x128 tile, 256 thr, BK=64, single-buffered 32 KB -> 5 blocks/CU.
// grid = 128*16 = 2048 blocks, chunked XCD swizzle (q=256). (unchanged)
// ---------------------------------------------------------------------------
__global__ __launch_bounds__(256)
void gemm2(const unsigned short* __restrict__ A,
           const unsigned short* __restrict__ Bt,
           const float* __restrict__ bias,
           float* __restrict__ C) {
    constexpr int N = 2048, Kd = 512, BK = 64, NSTEP = Kd / BK;  // 8 steps

    __shared__ __align__(16) unsigned short ldsA[128 * BK];  // 16 KB
    __shared__ __align__(16) unsigned short ldsB[128 * BK];  // 16 KB

    const int tid  = threadIdx.x;
    const int lane = tid & 63;
    const int wid  = tid >> 6;
    const int wr   = wid >> 1;
    const int wc   = wid & 1;

    const int bid = blockIdx.x;
    const int swz = ((bid & 7) << 8) + (bid >> 3);   // nwg=2048, q=256
    const int bn  = swz & 15;
    const int bm  = swz >> 4;
    const int brow = bm << 7;
    const int bcol = bn << 7;

    const int lrow = lane & 15;
    const int ku   = lane >> 4;
    const int rx   = lrow & 7;

    const int srow = tid >> 3;
    const int sgu  = (tid & 7) ^ (srow & 7);

    f32x4 acc[4][4] = {};

    auto stage = [&](int k0) {
#pragma unroll
        for (int i = 0; i < 4; ++i) {
            const int row = i * 32 + srow;
            const char* sa =
                (const char*)(A + (size_t)(brow + row) * Kd + k0) + (sgu << 4);
            const char* sb =
                (const char*)(Bt + (size_t)(bcol + row) * Kd + k0) + (sgu << 4);
            GLOAD_LDS16(sa, (char*)ldsA + i * 4096 + tid * 16);
            GLOAD_LDS16(sb, (char*)ldsB + i * 4096 + tid * 16);
        }
    };
    auto compute = [&]() {
#pragma unroll
        for (int kk = 0; kk < 2; ++kk) {
            const int un = ((ku + (kk << 2)) ^ rx) << 4;
            bf16x8 a[4], b[4];
#pragma unroll
            for (int m = 0; m < 4; ++m)
                a[m] = *(const bf16x8*)((const char*)ldsA +
                       ((wr << 6) + (m << 4) + lrow) * 128 + un);
#pragma unroll
            for (int n = 0; n < 4; ++n)
                b[n] = *(const bf16x8*)((const char*)ldsB +
                       ((wc << 6) + (n << 4) + lrow) * 128 + un);
#pragma unroll
            for (int m = 0; m < 4; ++m)
#pragma unroll
                for (int n = 0; n < 4; ++n)
                    acc[m][n] = __builtin_amdgcn_mfma_f32_16x16x32_bf16(
                        a[m], b[n], acc[m][n], 0, 0, 0);
        }
    };

    stage(0);
    __syncthreads();

    for (int t = 0; t < NSTEP; ++t) {
        compute();
        if (t + 1 < NSTEP) {
            __syncthreads();
            stage((t + 1) * BK);
            __syncthreads();
        }
    }

    const int r0 = (lane >> 4) << 2;
#pragma unroll
    for (int n = 0; n < 4; ++n) {
        const int col = bcol + (wc << 6) + (n << 4) + lrow;
        const float bb = bias[col];
#pragma unroll
        for (int m = 0; m < 4; ++m)
#pragma unroll
            for (int j = 0; j < 4; ++j) {
                const int row = brow + (wr << 6) + (m << 4) + r0 + j;
                C[(size_t)row * N + col] = acc[m][n][j] + bb;
            }
    }
}

extern "C" void kernel_launch(void* const* d_in, const int* in_sizes, int n_in,
                              void* d_out, int out_size, void* d_ws, size_t ws_size,
                              hipStream_t stream) {
    const float* X  = (const float*)d_in[0];   // [16384][2048]
    const float* W1 = (const float*)d_in[1];   // [512][2048]
    const float* b1 = (const float*)d_in[2];   // [512]
    const float* W2 = (const float*)d_in[3];   // [2048][512]
    const float* b2 = (const float*)d_in[4];   // [2048]

    const int B = 16384, M = 2048, Kd = 512;

    // workspace: W1bf (2MB), W2bf (2MB), Hbf (16.8MB)
    char* ws = (char*)d_ws;
    unsigned short* W1bf = (unsigned short*)ws;
    unsigned short* W2bf = W1bf + (size_t)Kd * M;
    unsigned short* Hbf  = W2bf + (size_t)M * Kd;

    // both weight casts in one launch: 2 * 256K float4s, one per thread
    cast_weights_bf16<<<2048, 256, 0, stream>>>(W1, W1bf, W2, W2bf,
                                                Kd * M / 4);

    gemm1_xcast<<<(B / 128) * (Kd / 128), 512, 0, stream>>>(X, W1bf, b1, Hbf);
    gemm2<<<(B / 128) * (M / 128), 256, 0, stream>>>(Hbf, W2bf, b2,
                                                     (float*)d_out);
}